// Round 1
// baseline (2217.711 us; speedup 1.0000x reference)
//
#include <hip/hip_runtime.h>
#include <math.h>

#define HH 256
#define WW 256
#define BATCH 8
#define HWSZ 65536
#define NPB 2048  // pixel-blocks = BATCH * HH rows

// One thread = one output pixel x COG output channels. Weight indices are
// block-uniform -> expect scalar loads. Per-block channel sum/sumsq partials
// written for BN stats (fused; no second pass over the feature map).
template<int CIN, int COUT, int COG, bool WRITE_OUT>
__global__ __launch_bounds__(256) void conv_bn_stats(
    const float* __restrict__ in, const float* __restrict__ wgt,
    const float* __restrict__ bias, float* __restrict__ out,
    float* __restrict__ partial)
{
  const int w  = threadIdx.x;      // 0..255 = full row, coalesced
  const int h  = blockIdx.x;       // 0..255
  const int b  = blockIdx.y;       // 0..7
  const int co0 = blockIdx.z * COG;

  // boundary masks/offsets depend only on (h,w): precompute once
  int off[9]; float msk[9];
  #pragma unroll
  for (int dh = -1; dh <= 1; ++dh) {
    #pragma unroll
    for (int dw = -1; dw <= 1; ++dw) {
      int t9 = (dh + 1) * 3 + (dw + 1);
      int hh = h + dh, ww = w + dw;
      bool ok = (hh >= 0) && (hh < HH) && (ww >= 0) && (ww < WW);
      int hc = min(max(hh, 0), HH - 1), wc = min(max(ww, 0), WW - 1);
      off[t9] = hc * WW + wc;
      msk[t9] = ok ? 1.0f : 0.0f;
    }
  }

  const float* inb = in + (size_t)b * CIN * HWSZ;
  float acc[COG];
  #pragma unroll
  for (int c = 0; c < COG; ++c) acc[c] = bias[co0 + c];

  for (int ci = 0; ci < CIN; ++ci) {
    const float* p = inb + (size_t)ci * HWSZ;
    float v[9];
    #pragma unroll
    for (int t = 0; t < 9; ++t) v[t] = p[off[t]] * msk[t];
    #pragma unroll
    for (int c = 0; c < COG; ++c) {
      const float* wr = wgt + ((size_t)(co0 + c) * CIN + ci) * 9;
      #pragma unroll
      for (int t = 0; t < 9; ++t)
        acc[c] = fmaf(wr[t], v[t], acc[c]);
    }
  }

  if constexpr (WRITE_OUT) {
    float* ob = out + ((size_t)b * COUT + co0) * HWSZ + h * WW + w;
    #pragma unroll
    for (int c = 0; c < COG; ++c) ob[(size_t)c * HWSZ] = acc[c];
  }

  // per-block channel stats: wave shuffle tree -> LDS across 4 waves -> partial
  __shared__ float red[4][COG][2];
  const int lane = threadIdx.x & 63, wv = threadIdx.x >> 6;
  #pragma unroll
  for (int c = 0; c < COG; ++c) {
    float s = acc[c], q = acc[c] * acc[c];
    #pragma unroll
    for (int o = 32; o > 0; o >>= 1) {
      s += __shfl_down(s, o);
      q += __shfl_down(q, o);
    }
    if (lane == 0) { red[wv][c][0] = s; red[wv][c][1] = q; }
  }
  __syncthreads();
  if (threadIdx.x < COG * 2) {
    int c = threadIdx.x >> 1, j = threadIdx.x & 1;
    float r = red[0][c][j] + red[1][c][j] + red[2][c][j] + red[3][c][j];
    int pb = b * (int)gridDim.x + blockIdx.x;  // 0..2047
    partial[((size_t)(co0 + c) * 2 + j) * NPB + pb] = r;
  }
}

// one block per channel: fold mean/var/gamma/beta into scale & shift
__global__ __launch_bounds__(256) void reduce_stats(
    const float* __restrict__ partial, const float* __restrict__ gamma,
    const float* __restrict__ beta, float* __restrict__ scale,
    float* __restrict__ shift)
{
  const int c = blockIdx.x;
  float s = 0.f, q = 0.f;
  for (int i = threadIdx.x; i < NPB; i += 256) {
    s += partial[((size_t)c * 2 + 0) * NPB + i];
    q += partial[((size_t)c * 2 + 1) * NPB + i];
  }
  #pragma unroll
  for (int o = 32; o > 0; o >>= 1) {
    s += __shfl_down(s, o);
    q += __shfl_down(q, o);
  }
  __shared__ float rs[4][2];
  const int lane = threadIdx.x & 63, wv = threadIdx.x >> 6;
  if (lane == 0) { rs[wv][0] = s; rs[wv][1] = q; }
  __syncthreads();
  if (threadIdx.x == 0) {
    s = rs[0][0] + rs[1][0] + rs[2][0] + rs[3][0];
    q = rs[0][1] + rs[1][1] + rs[2][1] + rs[3][1];
    const float N = (float)((size_t)BATCH * HWSZ);
    float mean = s / N;
    float var  = q / N - mean * mean;
    float rstd = 1.0f / sqrtf(var + 1e-5f);
    float sc   = gamma[c] * rstd;
    scale[c] = sc;
    shift[c] = beta[c] - mean * sc;
  }
}

// in-place z = leaky_relu(y*scale+shift), float4 vectorized
__global__ __launch_bounds__(256) void bn_lrelu(
    float* __restrict__ buf, const float* __restrict__ scale,
    const float* __restrict__ shift, int C)
{
  const int c = blockIdx.y, b = blockIdx.z;
  const float sc = scale[c], sh = shift[c];
  float4* p = (float4*)(buf + ((size_t)b * C + c) * HWSZ);
  const int i = blockIdx.x * 256 + threadIdx.x;  // < 16384
  float4 v = p[i];
  float y;
  y = v.x * sc + sh; v.x = fmaxf(y, 0.01f * y);
  y = v.y * sc + sh; v.y = fmaxf(y, 0.01f * y);
  y = v.z * sc + sh; v.z = fmaxf(y, 0.01f * y);
  y = v.w * sc + sh; v.w = fmaxf(y, 0.01f * y);
  p[i] = v;
}

// 3 x (8,3,7,7) raw-image patch gathers -> out[0..3528)
__global__ __launch_bounds__(256) void patches(
    const float* __restrict__ img, const int* __restrict__ axy,
    const int* __restrict__ pxy, const int* __restrict__ nxy,
    float* __restrict__ out)
{
  const int i = blockIdx.x * 256 + threadIdx.x;
  if (i >= 3 * BATCH * 3 * 49) return;
  const int arr = i / 1176, r = i % 1176;
  const int b = r / 147, q = r % 147;
  const int c = q / 49, s = q % 49;
  const int ph = s / 7, pw = s % 7;
  const int* xy = (arr == 0) ? axy : ((arr == 1) ? pxy : nxy);
  const int x = xy[(b * 32 + 31) * 2 + 0];
  const int y = xy[(b * 32 + 31) * 2 + 1];
  out[i] = img[((size_t)(b * 3 + c) * HH + (x - 3 + ph)) * WW + (y - 3 + pw)];
}

// conv3 recomputed at the 8 gather pixels (uses n_xy per reference!),
// then BN3 + lrelu -> out[3528..4552)
__global__ __launch_bounds__(128) void encode(
    const float* __restrict__ z2, const int* __restrict__ nxy,
    const float* __restrict__ wgt, const float* __restrict__ bias,
    const float* __restrict__ scale, const float* __restrict__ shift,
    float* __restrict__ out)
{
  const int b = blockIdx.x, co = threadIdx.x;
  const int x = nxy[(b * 32 + 31) * 2 + 0];
  const int y = nxy[(b * 32 + 31) * 2 + 1];
  float acc = bias[co];
  for (int ci = 0; ci < 64; ++ci) {
    const float* p = z2 + ((size_t)(b * 64 + ci) * HH + x) * WW + y;
    #pragma unroll
    for (int dh = -1; dh <= 1; ++dh) {
      #pragma unroll
      for (int dw = -1; dw <= 1; ++dw) {
        acc = fmaf(wgt[((size_t)co * 64 + ci) * 9 + (dh + 1) * 3 + (dw + 1)],
                   p[dh * WW + dw], acc);
      }
    }
  }
  const float yv = acc * scale[co] + shift[co];
  out[3528 + b * 128 + co] = fmaxf(yv, 0.01f * yv);
}

extern "C" void kernel_launch(void* const* d_in, const int* in_sizes, int n_in,
                              void* d_out, int out_size, void* d_ws, size_t ws_size,
                              hipStream_t stream)
{
  const float* image = (const float*)d_in[0];
  const int*   axy   = (const int*)d_in[1];
  const int*   pxy   = (const int*)d_in[2];
  const int*   nxy   = (const int*)d_in[3];
  const float* c1w = (const float*)d_in[4];
  const float* c1b = (const float*)d_in[5];
  const float* g1  = (const float*)d_in[6];
  const float* b1  = (const float*)d_in[7];
  const float* c2w = (const float*)d_in[8];
  const float* c2b = (const float*)d_in[9];
  const float* g2  = (const float*)d_in[10];
  const float* b2  = (const float*)d_in[11];
  const float* c3w = (const float*)d_in[12];
  const float* c3b = (const float*)d_in[13];
  const float* g3  = (const float*)d_in[14];
  const float* b3  = (const float*)d_in[15];
  float* out = (float*)d_out;

  // workspace layout (~204 MB total)
  float* buf1    = (float*)d_ws;                        // 8*32*65536 = 16.78M floats
  float* buf2    = buf1 + (size_t)8 * 32 * HWSZ;        // 8*64*65536 = 33.55M floats
  float* partial = buf2 + (size_t)8 * 64 * HWSZ;        // 128*2*2048 = 524288 floats
  float* scale1  = partial + (size_t)128 * 2 * NPB;
  float* shift1  = scale1 + 32;
  float* scale2  = shift1 + 32;
  float* shift2  = scale2 + 64;
  float* scale3  = shift2 + 64;
  float* shift3  = scale3 + 128;

  // layer 1: 3 -> 32
  conv_bn_stats<3, 32, 32, true><<<dim3(256, 8, 1), 256, 0, stream>>>(
      image, c1w, c1b, buf1, partial);
  reduce_stats<<<32, 256, 0, stream>>>(partial, g1, b1, scale1, shift1);
  bn_lrelu<<<dim3(64, 32, 8), 256, 0, stream>>>(buf1, scale1, shift1, 32);

  // layer 2: 32 -> 64
  conv_bn_stats<32, 64, 16, true><<<dim3(256, 8, 4), 256, 0, stream>>>(
      buf1, c2w, c2b, buf2, partial);
  reduce_stats<<<64, 256, 0, stream>>>(partial, g2, b2, scale2, shift2);
  bn_lrelu<<<dim3(64, 64, 8), 256, 0, stream>>>(buf2, scale2, shift2, 64);

  // layer 3: 64 -> 128, stats only (full output never stored)
  conv_bn_stats<64, 128, 16, false><<<dim3(256, 8, 8), 256, 0, stream>>>(
      buf2, c3w, c3b, nullptr, partial);
  reduce_stats<<<128, 256, 0, stream>>>(partial, g3, b3, scale3, shift3);

  // outputs
  patches<<<14, 256, 0, stream>>>(image, axy, pxy, nxy, out);
  encode<<<8, 128, 0, stream>>>(buf2, nxy, c3w, c3b, scale3, shift3, out);
}

// Round 2
// 367.283 us; speedup vs baseline: 6.0382x; 6.0382x over previous
//
#include <hip/hip_runtime.h>
#include <math.h>

#define HH 256
#define WW 256
#define BATCH 8
#define HWSZ 65536

typedef __attribute__((ext_vector_type(8))) short short8;
typedef __attribute__((ext_vector_type(4))) float floatx4;

__device__ __forceinline__ unsigned short f2bf(float f) {
  union { float f; unsigned int u; } v; v.f = f;
  unsigned int r = v.u + 0x7fff + ((v.u >> 16) & 1);
  return (unsigned short)(r >> 16);
}
__device__ __forceinline__ float bf2f(unsigned short u) {
  union { unsigned int u; float f; } v; v.u = ((unsigned int)u) << 16;
  return v.f;
}

// ---- weight pre-swizzle: OIHW fp32 -> MFMA B-fragment order bf16 ----------
// wf[(((tap*KC + kc)*NG + ng)*64 + lane)*8 + j] =
//     W[cout = ng*16 + (lane&15)][cin = kc*32 + (lane>>4)*8 + j][tap]
template<int CIN, int COUT>
__global__ __launch_bounds__(256) void prep_wfrag(
    const float* __restrict__ w, unsigned short* __restrict__ wf)
{
  constexpr int KC = CIN / 32, NG = COUT / 16;
  const int idx = blockIdx.x * 256 + threadIdx.x;
  if (idx >= 9 * CIN * COUT) return;
  const int j = idx & 7;
  const int lane = (idx >> 3) & 63;
  int rest = idx >> 9;
  const int ng = rest % NG; rest /= NG;
  const int kc = rest % KC; const int tap = rest / KC;
  const int cout = ng * 16 + (lane & 15);
  const int cin = kc * 32 + ((lane >> 4) << 3) + j;
  wf[idx] = f2bf(w[((size_t)cout * CIN + cin) * 9 + tap]);
}

// ---- conv1: 3->32, fp32 VALU, NHWC bf16 out via LDS transpose -------------
__global__ __launch_bounds__(256) void conv1_kernel(
    const float* __restrict__ in, const float* __restrict__ wgt,
    const float* __restrict__ bias, unsigned short* __restrict__ out,
    float* __restrict__ partial)
{
  const int w = threadIdx.x, h = blockIdx.x, b = blockIdx.y;
  int off[9]; float msk[9];
  #pragma unroll
  for (int dh = -1; dh <= 1; ++dh)
    #pragma unroll
    for (int dw = -1; dw <= 1; ++dw) {
      int t9 = (dh + 1) * 3 + (dw + 1);
      int hh = h + dh, ww = w + dw;
      bool ok = (hh >= 0) && (hh < HH) && (ww >= 0) && (ww < WW);
      int hc = min(max(hh, 0), HH - 1), wc = min(max(ww, 0), WW - 1);
      off[t9] = hc * WW + wc;
      msk[t9] = ok ? 1.0f : 0.0f;
    }
  const float* inb = in + (size_t)b * 3 * HWSZ;
  float acc[32];
  #pragma unroll
  for (int c = 0; c < 32; ++c) acc[c] = bias[c];
  for (int ci = 0; ci < 3; ++ci) {
    const float* p = inb + (size_t)ci * HWSZ;
    float v[9];
    #pragma unroll
    for (int t = 0; t < 9; ++t) v[t] = p[off[t]] * msk[t];
    #pragma unroll
    for (int c = 0; c < 32; ++c) {
      const float* wr = wgt + ((size_t)c * 3 + ci) * 9;
      #pragma unroll
      for (int t = 0; t < 9; ++t) acc[c] = fmaf(wr[t], v[t], acc[c]);
    }
  }
  // stats (fp32, pre-quantization)
  __shared__ float red[4][32][2];
  const int lane = threadIdx.x & 63, wv = threadIdx.x >> 6;
  #pragma unroll
  for (int c = 0; c < 32; ++c) {
    float s = acc[c], q = acc[c] * acc[c];
    #pragma unroll
    for (int o = 32; o > 0; o >>= 1) { s += __shfl_down(s, o); q += __shfl_down(q, o); }
    if (lane == 0) { red[wv][c][0] = s; red[wv][c][1] = q; }
  }
  // transpose NCHW-regs -> NHWC bf16 via LDS
  __shared__ unsigned int tr[256 * 17];
  #pragma unroll
  for (int i = 0; i < 16; ++i) {
    unsigned int lo = f2bf(acc[2 * i]), hi = f2bf(acc[2 * i + 1]);
    tr[w * 17 + i] = lo | (hi << 16);
  }
  __syncthreads();
  if (threadIdx.x < 64) {
    int c = threadIdx.x >> 1, j = threadIdx.x & 1;
    float r = red[0][c][j] + red[1][c][j] + red[2][c][j] + red[3][c][j];
    int pb = b * 256 + h;
    partial[((size_t)c * 2 + j) * 2048 + pb] = r;
  }
  unsigned int* o32 = (unsigned int*)out;
  const size_t base = (size_t)(b * 256 + h) * 4096;  // row * 256px * 32ch / 2
  #pragma unroll
  for (int k = 0; k < 16; ++k) {
    int fp = threadIdx.x + k * 256;
    o32[base + fp] = tr[(fp >> 4) * 17 + (fp & 15)];
  }
}

// ---- MFMA conv: CINxCOUT 3x3, bf16 NHWC in, bf16 NHWC out (optional) ------
// block = 256 thr = 4 waves (2x2), tile = 128 px x COUT, fused BN-stat partials
template<int CIN, int COUT, bool WRITE_OUT>
__global__ __launch_bounds__(256) void conv_mfma(
    const unsigned short* __restrict__ in, const unsigned short* __restrict__ wf,
    const float* __restrict__ bias, unsigned short* __restrict__ out,
    float* __restrict__ partial)
{
  constexpr int CPAD = CIN + 8;        // 16B-aligned px stride, 2-way banks
  constexpr int KC = CIN / 32;         // k-chunks per tap
  constexpr int NG = COUT / 16;        // global n-groups
  constexpr int NF = COUT / 32;        // n-frags per wave (2 waves in n)
  const int tid = threadIdx.x, lane = tid & 63, wv = tid >> 6;
  const int wave_m = wv >> 1, wave_n = wv & 1;
  const int h = blockIdx.y, b = blockIdx.z, w0 = blockIdx.x * 128;

  __shared__ unsigned short lds[3 * 130 * CPAD];

  // stage 3 rows x 130 px x CIN (zero-filled at borders)
  constexpr int CH8 = CIN / 8;
  constexpr int CHUNKS = 3 * 130 * CH8;
  const size_t inb = (size_t)b * HWSZ * CIN;
  for (int c = tid; c < CHUNKS; c += 256) {
    int r = c / (130 * CH8);
    int rem = c - r * (130 * CH8);
    int px = rem / CH8, cg = rem - px * CH8;
    int hi = h + r - 1, wi = w0 + px - 1;
    uint4 v = make_uint4(0, 0, 0, 0);
    if ((unsigned)hi < 256u && (unsigned)wi < 256u)
      v = *(const uint4*)(in + inb + ((size_t)hi * 256 + wi) * CIN + cg * 8);
    *(uint4*)&lds[(r * 130 + px) * CPAD + cg * 8] = v;
  }
  __syncthreads();

  floatx4 acc[4][NF];
  #pragma unroll
  for (int mf = 0; mf < 4; ++mf)
    #pragma unroll
    for (int nf = 0; nf < NF; ++nf) acc[mf][nf] = (floatx4){0.f, 0.f, 0.f, 0.f};

  const int base_px = wave_m * 64 + (lane & 15);
  const int k_lane = (lane >> 4) << 3;

  for (int tap = 0; tap < 9; ++tap) {
    const int row_off = (tap / 3) * 130 + (tap % 3);  // + dw slot shift
    #pragma unroll
    for (int kc = 0; kc < KC; ++kc) {
      short8 a[4];
      #pragma unroll
      for (int mf = 0; mf < 4; ++mf)
        a[mf] = *(const short8*)&lds[(row_off + base_px + mf * 16) * CPAD + kc * 32 + k_lane];
      short8 bg[NF];
      #pragma unroll
      for (int nf = 0; nf < NF; ++nf) {
        int ng = wave_n * NF + nf;
        bg[nf] = *(const short8*)&wf[((((tap * KC + kc) * NG) + ng) * 64 + lane) * 8];
      }
      #pragma unroll
      for (int mf = 0; mf < 4; ++mf)
        #pragma unroll
        for (int nf = 0; nf < NF; ++nf)
          acc[mf][nf] = __builtin_amdgcn_mfma_f32_16x16x32_bf16(a[mf], bg[nf], acc[mf][nf], 0, 0, 0);
    }
  }

  // epilogue: +bias, stats, optional bf16 NHWC store
  __shared__ float sred[4][NF][16], qred[4][NF][16];
  const size_t orow = ((size_t)(b * 256 + h) * 256 + w0);
  #pragma unroll
  for (int nf = 0; nf < NF; ++nf) {
    const int ch = wave_n * (COUT / 2) + nf * 16 + (lane & 15);
    const float bv = bias[ch];
    float sa = 0.f, qa = 0.f;
    #pragma unroll
    for (int mf = 0; mf < 4; ++mf) {
      #pragma unroll
      for (int r = 0; r < 4; ++r) {
        float y = acc[mf][nf][r] + bv;
        sa += y; qa += y * y;
        if constexpr (WRITE_OUT) {
          int p = wave_m * 64 + mf * 16 + ((lane >> 4) << 2) + r;
          out[(orow + p) * COUT + ch] = f2bf(y);
        }
      }
    }
    sa += __shfl_xor(sa, 16); sa += __shfl_xor(sa, 32);
    qa += __shfl_xor(qa, 16); qa += __shfl_xor(qa, 32);
    if (lane < 16) { sred[wv][nf][lane] = sa; qred[wv][nf][lane] = qa; }
  }
  __syncthreads();
  if (tid < COUT) {
    const int ch = tid;
    const int wn = ch / (COUT / 2), rr = ch % (COUT / 2);
    const int nf = rr >> 4, li = rr & 15;
    float s = sred[wn][nf][li] + sred[wn + 2][nf][li];
    float q = qred[wn][nf][li] + qred[wn + 2][nf][li];
    int blk = blockIdx.x + ((blockIdx.z << 8) + blockIdx.y) * 2;
    partial[((size_t)ch * 2 + 0) * 4096 + blk] = s;
    partial[((size_t)ch * 2 + 1) * 4096 + blk] = q;
  }
}

// ---- fold partials into scale/shift ---------------------------------------
__global__ __launch_bounds__(256) void reduce_stats(
    const float* __restrict__ partial, const float* __restrict__ gamma,
    const float* __restrict__ beta, float* __restrict__ scale,
    float* __restrict__ shift, int npb)
{
  const int c = blockIdx.x;
  float s = 0.f, q = 0.f;
  for (int i = threadIdx.x; i < npb; i += 256) {
    s += partial[((size_t)c * 2 + 0) * npb + i];
    q += partial[((size_t)c * 2 + 1) * npb + i];
  }
  #pragma unroll
  for (int o = 32; o > 0; o >>= 1) { s += __shfl_down(s, o); q += __shfl_down(q, o); }
  __shared__ float rs[4][2];
  const int lane = threadIdx.x & 63, wv = threadIdx.x >> 6;
  if (lane == 0) { rs[wv][0] = s; rs[wv][1] = q; }
  __syncthreads();
  if (threadIdx.x == 0) {
    s = rs[0][0] + rs[1][0] + rs[2][0] + rs[3][0];
    q = rs[0][1] + rs[1][1] + rs[2][1] + rs[3][1];
    const float N = (float)((size_t)BATCH * HWSZ);
    float mean = s / N;
    float var = q / N - mean * mean;
    float rstd = 1.0f / sqrtf(var + 1e-5f);
    float sc = gamma[c] * rstd;
    scale[c] = sc;
    shift[c] = beta[c] - mean * sc;
  }
}

// ---- in-place BN + leaky-relu on bf16 NHWC, 8 elems/thread ----------------
template<int C>
__global__ __launch_bounds__(256) void bn_lrelu_bf16(
    unsigned short* __restrict__ buf, const float* __restrict__ scale,
    const float* __restrict__ shift)
{
  const int idx8 = blockIdx.x * 256 + threadIdx.x;
  const int ch0 = (idx8 << 3) & (C - 1);
  const float4 sc0 = *(const float4*)&scale[ch0];
  const float4 sc1 = *(const float4*)&scale[ch0 + 4];
  const float4 sh0 = *(const float4*)&shift[ch0];
  const float4 sh1 = *(const float4*)&shift[ch0 + 4];
  uint4 v = ((uint4*)buf)[idx8];
  float scs[8] = {sc0.x, sc0.y, sc0.z, sc0.w, sc1.x, sc1.y, sc1.z, sc1.w};
  float shs[8] = {sh0.x, sh0.y, sh0.z, sh0.w, sh1.x, sh1.y, sh1.z, sh1.w};
  unsigned int* u = (unsigned int*)&v;
  #pragma unroll
  for (int p = 0; p < 4; ++p) {
    float a = bf2f((unsigned short)(u[p] & 0xffff));
    float bb = bf2f((unsigned short)(u[p] >> 16));
    float ya = a * scs[2 * p] + shs[2 * p];
    float yb = bb * scs[2 * p + 1] + shs[2 * p + 1];
    ya = fmaxf(ya, 0.01f * ya);
    yb = fmaxf(yb, 0.01f * yb);
    u[p] = (unsigned int)f2bf(ya) | ((unsigned int)f2bf(yb) << 16);
  }
  ((uint4*)buf)[idx8] = v;
}

// ---- raw-image patch gathers -> out[0..3528) ------------------------------
__global__ __launch_bounds__(256) void patches(
    const float* __restrict__ img, const int* __restrict__ axy,
    const int* __restrict__ pxy, const int* __restrict__ nxy,
    float* __restrict__ out)
{
  const int i = blockIdx.x * 256 + threadIdx.x;
  if (i >= 3 * BATCH * 3 * 49) return;
  const int arr = i / 1176, r = i % 1176;
  const int b = r / 147, q = r % 147;
  const int c = q / 49, s = q % 49;
  const int ph = s / 7, pw = s % 7;
  const int* xy = (arr == 0) ? axy : ((arr == 1) ? pxy : nxy);
  const int x = xy[(b * 32 + 31) * 2 + 0];
  const int y = xy[(b * 32 + 31) * 2 + 1];
  out[i] = img[((size_t)(b * 3 + c) * HH + (x - 3 + ph)) * WW + (y - 3 + pw)];
}

// ---- conv3 recomputed at 8 pixels (n_xy!), BN3+lrelu -> out[3528..4552) ---
__global__ __launch_bounds__(128) void encode(
    const unsigned short* __restrict__ z2, const int* __restrict__ nxy,
    const float* __restrict__ wgt, const float* __restrict__ bias,
    const float* __restrict__ scale, const float* __restrict__ shift,
    float* __restrict__ out)
{
  const int b = blockIdx.x, co = threadIdx.x;
  const int x = nxy[(b * 32 + 31) * 2 + 0];
  const int y = nxy[(b * 32 + 31) * 2 + 1];
  float acc = bias[co];
  for (int ci = 0; ci < 64; ++ci) {
    #pragma unroll
    for (int dh = -1; dh <= 1; ++dh)
      #pragma unroll
      for (int dw = -1; dw <= 1; ++dw) {
        float v = bf2f(z2[((size_t)(b * 256 + x + dh) * 256 + (y + dw)) * 64 + ci]);
        acc = fmaf(wgt[((size_t)co * 64 + ci) * 9 + (dh + 1) * 3 + (dw + 1)], v, acc);
      }
  }
  const float yv = acc * scale[co] + shift[co];
  out[3528 + b * 128 + co] = fmaxf(yv, 0.01f * yv);
}

extern "C" void kernel_launch(void* const* d_in, const int* in_sizes, int n_in,
                              void* d_out, int out_size, void* d_ws, size_t ws_size,
                              hipStream_t stream)
{
  const float* image = (const float*)d_in[0];
  const int* axy = (const int*)d_in[1];
  const int* pxy = (const int*)d_in[2];
  const int* nxy = (const int*)d_in[3];
  const float* c1w = (const float*)d_in[4];
  const float* c1b = (const float*)d_in[5];
  const float* g1 = (const float*)d_in[6];
  const float* b1 = (const float*)d_in[7];
  const float* c2w = (const float*)d_in[8];
  const float* c2b = (const float*)d_in[9];
  const float* g2 = (const float*)d_in[10];
  const float* b2 = (const float*)d_in[11];
  const float* c3w = (const float*)d_in[12];
  const float* c3b = (const float*)d_in[13];
  const float* g3 = (const float*)d_in[14];
  const float* b3 = (const float*)d_in[15];
  float* out = (float*)d_out;

  // workspace layout (~105 MB)
  unsigned short* zb1 = (unsigned short*)d_ws;            // 16.78M bf16 (34MB)
  unsigned short* zb2 = zb1 + (size_t)8 * 32 * HWSZ;      // 33.55M bf16 (67MB)
  unsigned short* wf2 = zb2 + (size_t)8 * 64 * HWSZ;      // 18432
  unsigned short* wf3 = wf2 + 18432;                      // 73728
  float* partial = (float*)(wf3 + 73728);                 // up to 1,048,576 floats
  float* scale1 = partial + (size_t)128 * 2 * 4096;
  float* shift1 = scale1 + 32;
  float* scale2 = shift1 + 32;
  float* shift2 = scale2 + 64;
  float* scale3 = shift2 + 64;
  float* shift3 = scale3 + 128;

  prep_wfrag<32, 64><<<72, 256, 0, stream>>>(c2w, wf2);
  prep_wfrag<64, 128><<<288, 256, 0, stream>>>(c3w, wf3);

  // layer 1: 3 -> 32 (VALU fp32, bf16 NHWC out)
  conv1_kernel<<<dim3(256, 8), 256, 0, stream>>>(image, c1w, c1b, zb1, partial);
  reduce_stats<<<32, 256, 0, stream>>>(partial, g1, b1, scale1, shift1, 2048);
  bn_lrelu_bf16<32><<<8192, 256, 0, stream>>>(zb1, scale1, shift1);

  // layer 2: 32 -> 64 (MFMA)
  conv_mfma<32, 64, true><<<dim3(2, 256, 8), 256, 0, stream>>>(zb1, wf2, c2b, zb2, partial);
  reduce_stats<<<64, 256, 0, stream>>>(partial, g2, b2, scale2, shift2, 4096);
  bn_lrelu_bf16<64><<<16384, 256, 0, stream>>>(zb2, scale2, shift2);

  // layer 3: 64 -> 128 (MFMA, stats only, output never stored)
  conv_mfma<64, 128, false><<<dim3(2, 256, 8), 256, 0, stream>>>(zb2, wf3, c3b, nullptr, partial);
  reduce_stats<<<128, 256, 0, stream>>>(partial, g3, b3, scale3, shift3, 4096);

  // outputs
  patches<<<14, 256, 0, stream>>>(image, axy, pxy, nxy, out);
  encode<<<8, 128, 0, stream>>>(zb2, nxy, c3w, c3b, scale3, shift3, out);
}